// Round 5
// baseline (97.271 us; speedup 1.0000x reference)
//
#include <hip/hip_runtime.h>

#define NN 2048
#define BB 4
#define IN_F 128
#define OUT_F 64

typedef __attribute__((ext_vector_type(8))) short short8;
typedef __attribute__((ext_vector_type(4))) float f32x4;
typedef __attribute__((ext_vector_type(4))) int i32x4;

__device__ __forceinline__ ushort f2bf(float f) {
  uint u = __float_as_uint(f);
  uint r = (u + 0x7fffu + ((u >> 16) & 1u)) >> 16;   // RNE, finite values
  return (ushort)r;
}
__device__ __forceinline__ float bf2f(ushort s) {
  return __uint_as_float(((uint)s) << 16);
}

// Kernel 1 (fused): per 32-row tile: wh = h@W (f32), el/er wave-reduce,
// bf16 transpose through LDS -> WhbfT[b][o][j] directly (no Whbf buffer).
__global__ __launch_bounds__(256) void wh_fused_kernel(
    const float* __restrict__ h, const float* __restrict__ W,
    const float* __restrict__ a, ushort* __restrict__ WhbfT,
    float* __restrict__ el, float* __restrict__ er) {
  __shared__ ushort whs[32][72];    // [j-local][o], padded
  int b = blockIdx.x >> 6;          // NN/32 = 64 tiles per batch
  int j0 = (blockIdx.x & 63) << 5;
  int tid = threadIdx.x;
  int o = tid & 63, g = tid >> 6;   // wave g -> rows g*8 .. g*8+7
  float al = a[o], ar = a[OUT_F + o];
  for (int m = 0; m < 8; ++m) {
    int jl = g * 8 + m;
    const float* hr = h + ((size_t)b * NN + j0 + jl) * IN_F;
    float wh = 0.f;
    #pragma unroll 8
    for (int f = 0; f < IN_F; ++f) wh += hr[f] * W[f * OUT_F + o];  // hr uniform
    whs[jl][o] = f2bf(wh);
    float vl = wh * al, vr = wh * ar;
    #pragma unroll
    for (int d = 32; d > 0; d >>= 1) {
      vl += __shfl_down(vl, d);
      vr += __shfl_down(vr, d);
    }
    if (o == 0) { el[(size_t)b * NN + j0 + jl] = vl; er[(size_t)b * NN + j0 + jl] = vr; }
  }
  __syncthreads();
  int o2 = tid & 63, c = tid >> 6;   // j-chunk c*8
  uint out[4];
  #pragma unroll
  for (int m = 0; m < 8; m += 2) {
    uint u0 = whs[c * 8 + m][o2], u1 = whs[c * 8 + m + 1][o2];
    out[m >> 1] = u0 | (u1 << 16);
  }
  *(uint4*)(WhbfT + ((size_t)(b * OUT_F + o2)) * NN + j0 + c * 8) = *(uint4*)out;
}

// Kernel 2: block = 16 rows of one batch, 1024 threads (16 waves).
// Lane layout: r = lane&15 (graph row), s = lane>>4 (k-slot); wave w owns
// k-strip [w*128, w*128+128). Each lane's 32 exp values (bf16, UNNORMALIZED)
// are exactly the MFMA A-fragments for its 4 k-blocks -> NO p LDS AT ALL.
// Row sums: 2x shfl_xor + 1KB cross-wave psum. Attention stores issue after
// the single barrier and overlap the MFMA phase; 1/s scaling is deferred to
// the epilogue (h' = inv * sum(exp*Wh)). C-reduce via LDS f32 atomics.
__global__ __launch_bounds__(1024, 2) void attn_kernel(
    const int* __restrict__ adj, const ushort* __restrict__ WhbfT,
    const float* __restrict__ el, const float* __restrict__ er,
    float* __restrict__ attn_out, float* __restrict__ hprime) {
  __shared__ float psum[16][16];       // [wave][row] partial exp-sums
  __shared__ float sacc[16][68];       // padded C accumulator [row][o]
  __shared__ float sinv[16];

  int blk = blockIdx.x;
  int b = blk >> 7;                    // 128 blocks per batch
  int i0 = (blk & 127) << 4;
  int tid = threadIdx.x;
  int w = tid >> 6, L = tid & 63;
  int r = L & 15, s = L >> 4;
  int i = i0 + r;
  int k0 = w * 128 + s * 8;

  const int* arow = adj + ((size_t)(b * NN + i)) * NN + k0;
  const float* erp = er + (size_t)b * NN + k0;
  float eli = el[(size_t)b * NN + i];

  // ---- Phase 1: streaming masked exp (no max pass; |e| <~ 12, f32-safe) ----
  short8 pv[4];
  float ssum = 0.f;
  #pragma unroll
  for (int t = 0; t < 4; ++t) {
    i32x4 a0 = *(const i32x4*)(arow + t * 32);
    i32x4 a1 = *(const i32x4*)(arow + t * 32 + 4);
    f32x4 e0 = *(const f32x4*)(erp + t * 32);
    f32x4 e1 = *(const f32x4*)(erp + t * 32 + 4);
    float pe[8];
    float ev[8] = {e0.x, e0.y, e0.z, e0.w, e1.x, e1.y, e1.z, e1.w};
    int   av[8] = {a0.x, a0.y, a0.z, a0.w, a1.x, a1.y, a1.z, a1.w};
    #pragma unroll
    for (int j = 0; j < 8; ++j) {
      float e = eli + ev[j];
      e = e > 0.f ? e : 0.2f * e;          // leaky_relu 0.2
      float x = __expf(e);
      pe[j] = av[j] > 0 ? x : 0.f;         // masked -> contributes 0
      ssum += pe[j];
    }
    short8 pk;
    #pragma unroll
    for (int j = 0; j < 8; ++j) pk[j] = (short)f2bf(pe[j]);
    pv[t] = pk;
  }
  ssum += __shfl_xor(ssum, 16);
  ssum += __shfl_xor(ssum, 32);          // row-partial sum in all 4 s-lanes
  if (L < 16) psum[w][L] = ssum;
  sacc[w][L] = 0.f;                      // zero C accumulator (cols 0..63)
  __syncthreads();

  float sfull = 0.f;
  #pragma unroll
  for (int w2 = 0; w2 < 16; ++w2) sfull += psum[w2][r];
  float inv = 1.f / sfull;
  if (w == 0 && L < 16) sinv[L] = inv;

  // ---- attention out (overlaps the MFMA phase below) ----
  float* orow = attn_out + ((size_t)(b * NN + i)) * NN + k0;
  #pragma unroll
  for (int t = 0; t < 4; ++t) {
    f32x4 v0, v1;
    v0.x = bf2f((ushort)pv[t][0]) * inv;
    v0.y = bf2f((ushort)pv[t][1]) * inv;
    v0.z = bf2f((ushort)pv[t][2]) * inv;
    v0.w = bf2f((ushort)pv[t][3]) * inv;
    v1.x = bf2f((ushort)pv[t][4]) * inv;
    v1.y = bf2f((ushort)pv[t][5]) * inv;
    v1.z = bf2f((ushort)pv[t][6]) * inv;
    v1.w = bf2f((ushort)pv[t][7]) * inv;
    __builtin_nontemporal_store(v0, (f32x4*)(orow + t * 32));
    __builtin_nontemporal_store(v1, (f32x4*)(orow + t * 32 + 4));
  }

  // ---- Phase 2: MFMA partial PV over this wave's k-strip ----
  const ushort* bbase = WhbfT + (size_t)b * OUT_F * NN;
  #pragma unroll
  for (int ot = 0; ot < 4; ++ot) {
    const ushort* brow = bbase + ((size_t)(ot * 16 + r)) * NN + k0;
    f32x4 acc = {0.f, 0.f, 0.f, 0.f};
    #pragma unroll
    for (int t = 0; t < 4; ++t) {
      short8 bf = *(const short8*)(brow + t * 32);
      acc = __builtin_amdgcn_mfma_f32_16x16x32_bf16(pv[t], bf, acc, 0, 0, 0);
    }
    #pragma unroll
    for (int q = 0; q < 4; ++q)
      atomicAdd(&sacc[s * 4 + q][ot * 16 + r], acc[q]);  // C: row=s*4+q, col=L&15
  }
  __syncthreads();

  // ---- epilogue: scale by inv, leaky_relu 0.01, store ----
  {
    int row = tid >> 6, col = tid & 63;
    float v = sacc[row][col] * sinv[row];
    v = v > 0.f ? v : 0.01f * v;
    hprime[((size_t)(b * NN + i0 + row)) * OUT_F + col] = v;
  }
}

extern "C" void kernel_launch(void* const* d_in, const int* in_sizes, int n_in,
                              void* d_out, int out_size, void* d_ws, size_t ws_size,
                              hipStream_t stream) {
  const float* h  = (const float*)d_in[0];
  const int* adj  = (const int*)d_in[1];
  const float* W  = (const float*)d_in[2];
  const float* a  = (const float*)d_in[3];

  float* hprime   = (float*)d_out;                           // B*N*OUT_F
  float* attn_out = (float*)d_out + (size_t)BB * NN * OUT_F; // B*N*N

  // workspace: WhbfT bf16 [B*64*N] (1 MB), el f32, er f32
  ushort* WhbfT = (ushort*)d_ws;
  float* el = (float*)(WhbfT + (size_t)BB * OUT_F * NN);
  float* er = el + (size_t)BB * NN;

  hipLaunchKernelGGL(wh_fused_kernel, dim3(BB * (NN / 32)), dim3(256), 0, stream,
                     h, W, a, WhbfT, el, er);
  hipLaunchKernelGGL(attn_kernel, dim3(BB * (NN / 16)), dim3(1024), 0, stream,
                     adj, WhbfT, el, er, attn_out, hprime);
}

// Round 6
// 68.031 us; speedup vs baseline: 1.4298x; 1.4298x over previous
//
#include <hip/hip_runtime.h>

#define NN 2048
#define BB 4
#define IN_F 128
#define OUT_F 64

typedef __attribute__((ext_vector_type(8))) short short8;
typedef __attribute__((ext_vector_type(4))) float f32x4;
typedef __attribute__((ext_vector_type(4))) int i32x4;

__device__ __forceinline__ ushort f2bf(float f) {
  uint u = __float_as_uint(f);
  uint r = (u + 0x7fffu + ((u >> 16) & 1u)) >> 16;   // RNE, finite values
  return (ushort)r;
}
__device__ __forceinline__ float bf2f(ushort s) {
  return __uint_as_float(((uint)s) << 16);
}

// Kernel 1 (fused): per 32-row tile: wh = h@W (f32), el/er wave-reduce,
// bf16 transpose through LDS -> WhbfT[b][o][j] directly.
__global__ __launch_bounds__(256) void wh_fused_kernel(
    const float* __restrict__ h, const float* __restrict__ W,
    const float* __restrict__ a, ushort* __restrict__ WhbfT,
    float* __restrict__ el, float* __restrict__ er) {
  __shared__ ushort whs[32][72];    // [j-local][o], padded
  int b = blockIdx.x >> 6;          // NN/32 = 64 tiles per batch
  int j0 = (blockIdx.x & 63) << 5;
  int tid = threadIdx.x;
  int o = tid & 63, g = tid >> 6;   // wave g -> rows g*8 .. g*8+7
  float al = a[o], ar = a[OUT_F + o];
  for (int m = 0; m < 8; ++m) {
    int jl = g * 8 + m;
    const float* hr = h + ((size_t)b * NN + j0 + jl) * IN_F;
    float wh = 0.f;
    #pragma unroll 8
    for (int f = 0; f < IN_F; ++f) wh += hr[f] * W[f * OUT_F + o];  // hr uniform
    whs[jl][o] = f2bf(wh);
    float vl = wh * al, vr = wh * ar;
    #pragma unroll
    for (int d = 32; d > 0; d >>= 1) {
      vl += __shfl_down(vl, d);
      vr += __shfl_down(vr, d);
    }
    if (o == 0) { el[(size_t)b * NN + j0 + jl] = vl; er[(size_t)b * NN + j0 + jl] = vr; }
  }
  __syncthreads();
  int o2 = tid & 63, c = tid >> 6;   // j-chunk c*8
  uint out[4];
  #pragma unroll
  for (int m = 0; m < 8; m += 2) {
    uint u0 = whs[c * 8 + m][o2], u1 = whs[c * 8 + m + 1][o2];
    out[m >> 1] = u0 | (u1 << 16);
  }
  *(uint4*)(WhbfT + ((size_t)(b * OUT_F + o2)) * NN + j0 + c * 8) = *(uint4*)out;
}

// Kernel 2: block = 16 rows of one batch, 512 threads (8 waves).
// er staged once in LDS (8 KB). Phase 1: wave w -> rows 2w,2w+1, COALESCED
// j-sweep; no-max streaming exp; unnormalized bf16 p kept packed in regs AND
// written XOR-swizzled to LDS. Phase 2: MFMA p @ Wh (wave = ntile x khalf).
// Attention stores issue AFTER the MFMA phase (drain overlaps phase 2 + epi).
__global__ __launch_bounds__(512, 4) void attn_kernel(
    const int* __restrict__ adj, const ushort* __restrict__ WhbfT,
    const float* __restrict__ el, const float* __restrict__ er,
    float* __restrict__ attn_out, float* __restrict__ hprime) {
  __shared__ __align__(16) char pbuf[16 * 4096];  // 64 KB: p bf16 [16][2048]
  __shared__ float ers[NN];                       // 8 KB
  __shared__ float red[4][16][17];                // 4.3 KB cross-khalf reduce
  __shared__ float sinv[16];

  int blk = blockIdx.x;
  int b = blk >> 7;             // 128 blocks per batch
  int i0 = (blk & 127) << 4;
  int tid = threadIdx.x;
  int wave = tid >> 6, lane = tid & 63;

  // stage er for this batch into LDS (512 x float4 = 2048 floats)
  ((f32x4*)ers)[tid] = ((const f32x4*)(er + (size_t)b * NN))[tid];
  __syncthreads();

  // ---- Phase 1: streaming masked exp, 2 rows per wave, coalesced ----
  uint2 pva[2][8];
  float invr[2];
  #pragma unroll
  for (int rr = 0; rr < 2; ++rr) {
    int r = wave * 2 + rr;
    int i = i0 + r;
    float eli = el[(size_t)b * NN + i];
    const i32x4* arow4 = (const i32x4*)(adj + ((size_t)(b * NN + i)) * NN);

    float ssum = 0.f;
    #pragma unroll
    for (int it = 0; it < 8; ++it) {
      i32x4 av = arow4[lane + 64 * it];
      f32x4 ev = *(const f32x4*)&ers[(lane + 64 * it) * 4];
      float pe[4];
      float evv[4] = {ev.x, ev.y, ev.z, ev.w};
      int   avv[4] = {av.x, av.y, av.z, av.w};
      #pragma unroll
      for (int k = 0; k < 4; ++k) {
        float e = eli + evv[k];
        e = e > 0.f ? e : 0.2f * e;          // leaky_relu 0.2
        float x = __expf(e);
        pe[k] = avv[k] > 0 ? x : 0.f;        // masked -> 0
        ssum += pe[k];
      }
      uint2 w2;
      w2.x = (uint)f2bf(pe[0]) | ((uint)f2bf(pe[1]) << 16);
      w2.y = (uint)f2bf(pe[2]) | ((uint)f2bf(pe[3]) << 16);
      pva[rr][it] = w2;
    }
    #pragma unroll
    for (int d = 32; d > 0; d >>= 1) ssum += __shfl_xor(ssum, d);
    float inv = 1.f / ssum;
    invr[rr] = inv;
    if (lane == 0) sinv[r] = inv;

    char* prow = pbuf + r * 4096;
    int sw = (r & 7) << 4;
    #pragma unroll
    for (int it = 0; it < 8; ++it)
      *(uint2*)(prow + (((lane + 64 * it) * 8) ^ sw)) = pva[rr][it];
  }
  __syncthreads();

  // ---- Phase 2: MFMA p @ Wh; wave = (ntile = w>>1, khalf = w&1) ----
  int ntile = wave >> 1, khalf = wave & 1;
  int o0 = ntile * 16;
  int lo16 = lane & 15, hi4 = lane >> 4;

  const char* prowA = pbuf + lo16 * 4096;
  int swA = (lo16 & 7) << 4;
  const ushort* brow = WhbfT + ((size_t)(b * OUT_F + o0 + lo16)) * NN;

  f32x4 acc = {0.f, 0.f, 0.f, 0.f};
  #pragma unroll 4
  for (int kk = 0; kk < 32; ++kk) {
    int kbase = khalf * 1024 + kk * 32 + hi4 * 8;
    short8 afrag = *(const short8*)(prowA + ((kbase * 2) ^ swA));
    short8 bfrag = *(const short8*)(brow + kbase);
    acc = __builtin_amdgcn_mfma_f32_16x16x32_bf16(afrag, bfrag, acc, 0, 0, 0);
  }

  // ---- attention stores (normalized); drain overlaps epilogue ----
  #pragma unroll
  for (int rr = 0; rr < 2; ++rr) {
    int i = i0 + wave * 2 + rr;
    float inv = invr[rr];
    f32x4* orow4 = (f32x4*)(attn_out + ((size_t)(b * NN + i)) * NN);
    #pragma unroll
    for (int it = 0; it < 8; ++it) {
      uint2 w2 = pva[rr][it];
      f32x4 v;
      v.x = bf2f((ushort)(w2.x & 0xffff)) * inv;
      v.y = bf2f((ushort)(w2.x >> 16)) * inv;
      v.z = bf2f((ushort)(w2.y & 0xffff)) * inv;
      v.w = bf2f((ushort)(w2.y >> 16)) * inv;
      __builtin_nontemporal_store(v, &orow4[lane + 64 * it]);
    }
  }

  // ---- cross-khalf reduce + epilogue ----
  if (khalf == 1) {
    #pragma unroll
    for (int q = 0; q < 4; ++q) red[ntile][hi4 * 4 + q][lo16] = acc[q];
  }
  __syncthreads();
  if (khalf == 0) {
    #pragma unroll
    for (int q = 0; q < 4; ++q) {
      int crow = hi4 * 4 + q;
      float v = (acc[q] + red[ntile][crow][lo16]) * sinv[crow];
      v = v > 0.f ? v : 0.01f * v;                     // leaky_relu 0.01
      hprime[((size_t)(b * NN + i0 + crow)) * OUT_F + o0 + lo16] = v;
    }
  }
}

extern "C" void kernel_launch(void* const* d_in, const int* in_sizes, int n_in,
                              void* d_out, int out_size, void* d_ws, size_t ws_size,
                              hipStream_t stream) {
  const float* h  = (const float*)d_in[0];
  const int* adj  = (const int*)d_in[1];
  const float* W  = (const float*)d_in[2];
  const float* a  = (const float*)d_in[3];

  float* hprime   = (float*)d_out;                           // B*N*OUT_F
  float* attn_out = (float*)d_out + (size_t)BB * NN * OUT_F; // B*N*N

  // workspace: WhbfT bf16 [B*64*N] (1 MB), el f32, er f32
  ushort* WhbfT = (ushort*)d_ws;
  float* el = (float*)(WhbfT + (size_t)BB * OUT_F * NN);
  float* er = el + (size_t)BB * NN;

  hipLaunchKernelGGL(wh_fused_kernel, dim3(BB * (NN / 32)), dim3(256), 0, stream,
                     h, W, a, WhbfT, el, er);
  hipLaunchKernelGGL(attn_kernel, dim3(BB * (NN / 16)), dim3(512), 0, stream,
                     adj, WhbfT, el, er, attn_out, hprime);
}

// Round 7
// 61.484 us; speedup vs baseline: 1.5821x; 1.1065x over previous
//
#include <hip/hip_runtime.h>

#define NN 2048
#define BB 4
#define IN_F 128
#define OUT_F 64

typedef __attribute__((ext_vector_type(8))) short short8;
typedef __attribute__((ext_vector_type(4))) float f32x4;
typedef __attribute__((ext_vector_type(4))) int i32x4;

__device__ __forceinline__ ushort f2bf(float f) {
  uint u = __float_as_uint(f);
  uint r = (u + 0x7fffu + ((u >> 16) & 1u)) >> 16;   // RNE, finite values
  return (ushort)r;
}
__device__ __forceinline__ float bf2f(ushort s) {
  return __uint_as_float(((uint)s) << 16);
}

// Kernel 1: per row: wh[o] = h[row].W[:,o] (f32) -> Whbf bf16 row-major;
// el/er via wave reduce. (round-3 structure: 8192 x 64, measured ~5 us)
__global__ __launch_bounds__(64) void wh_el_er_kernel(
    const float* __restrict__ h, const float* __restrict__ W,
    const float* __restrict__ a, ushort* __restrict__ Whbf,
    float* __restrict__ el, float* __restrict__ er) {
  int row = blockIdx.x;           // b*NN + n
  int o = threadIdx.x;
  const float* hr = h + (size_t)row * IN_F;
  float wh = 0.f;
  #pragma unroll 8
  for (int f = 0; f < IN_F; ++f) wh += hr[f] * W[f * OUT_F + o];
  Whbf[(size_t)row * OUT_F + o] = f2bf(wh);
  float vl = wh * a[o];
  float vr = wh * a[OUT_F + o];
  #pragma unroll
  for (int d = 32; d > 0; d >>= 1) {
    vl += __shfl_down(vl, d);
    vr += __shfl_down(vr, d);
  }
  if (o == 0) { el[row] = vl; er[row] = vr; }
}

// Kernel 1b: WhbfT[b][o][j] = Whbf[b][j][o] (bf16 transpose, 64x2048/batch).
__global__ __launch_bounds__(256) void transpose_kernel(
    const ushort* __restrict__ Whbf, ushort* __restrict__ WhbfT) {
  __shared__ uint tile[64][65];
  int b = blockIdx.x >> 5;
  int j0 = (blockIdx.x & 31) << 6;
  int t = threadIdx.x;
  int o = t & 63, jg = t >> 6;
  #pragma unroll
  for (int m = 0; m < 16; ++m) {
    int jj = jg * 16 + m;
    tile[jj][o] = (uint)Whbf[((size_t)(b * NN + j0 + jj)) * OUT_F + o];
  }
  __syncthreads();
  int oo = t >> 2, grp = t & 3;
  uint out[8];
  #pragma unroll
  for (int m = 0; m < 16; m += 2) {
    uint u0 = tile[grp * 16 + m][oo];
    uint u1 = tile[grp * 16 + m + 1][oo];
    out[m >> 1] = u0 | (u1 << 16);
  }
  uint4* dst = (uint4*)(WhbfT + ((size_t)(b * OUT_F + oo)) * NN + j0 + grp * 16);
  dst[0] = *(uint4*)&out[0];
  dst[1] = *(uint4*)&out[4];
}

// Kernel 2: block = 8 rows of one batch, 512 threads (8 waves), 1 row/wave.
// LDS ~37 KB -> 4 blocks/CU = 32 waves/CU (100% cap).
// Phase 1: coalesced streaming masked exp (no max pass), unnormalized bf16 p
//          packed in regs + XOR-swizzled into 32 KB pbuf.
// Then: barrier -> NT attention stores issue FIRST (drain overlaps MFMA) ->
// Phase 2: MFMA p @ Wh, wave = (ntile, khalf); A rows 8..15 zeroed (cndmask).
// Cross-khalf reduce in red[], scale by 1/s, lrelu 0.01.
__global__ __launch_bounds__(512, 8) void attn_kernel(
    const int* __restrict__ adj, const ushort* __restrict__ WhbfT,
    const float* __restrict__ el, const float* __restrict__ er,
    float* __restrict__ attn_out, float* __restrict__ hprime) {
  __shared__ __align__(16) char pbuf[8 * 4096];   // 32 KB: p bf16 [8][2048]
  __shared__ float red[4][16][17];                // 4.4 KB cross-khalf reduce
  __shared__ float sinv[8];

  int blk = blockIdx.x;
  int b = blk >> 8;             // 256 blocks per batch
  int i0 = (blk & 255) << 3;    // *8
  int tid = threadIdx.x;
  int w = tid >> 6, lane = tid & 63;

  // ---- Phase 1: streaming masked exp, 1 row per wave, coalesced ----
  int i = i0 + w;
  float eli = el[(size_t)b * NN + i];
  const i32x4* arow4 = (const i32x4*)(adj + ((size_t)(b * NN + i)) * NN);
  const f32x4* er4 = (const f32x4*)(er + (size_t)b * NN);

  uint2 pva[8];
  float ssum = 0.f;
  #pragma unroll
  for (int it = 0; it < 8; ++it) {
    i32x4 av = arow4[lane + 64 * it];
    f32x4 ev = er4[lane + 64 * it];
    float pe[4];
    float evv[4] = {ev.x, ev.y, ev.z, ev.w};
    int   avv[4] = {av.x, av.y, av.z, av.w};
    #pragma unroll
    for (int k = 0; k < 4; ++k) {
      float e = eli + evv[k];
      e = e > 0.f ? e : 0.2f * e;          // leaky_relu 0.2
      float x = __expf(e);                 // |e| <~ 12, f32-safe unnormalized
      pe[k] = avv[k] > 0 ? x : 0.f;        // masked -> 0
      ssum += pe[k];
    }
    uint2 w2;
    w2.x = (uint)f2bf(pe[0]) | ((uint)f2bf(pe[1]) << 16);
    w2.y = (uint)f2bf(pe[2]) | ((uint)f2bf(pe[3]) << 16);
    pva[it] = w2;
  }
  #pragma unroll
  for (int d = 32; d > 0; d >>= 1) ssum += __shfl_xor(ssum, d);
  float inv = 1.f / ssum;
  if (lane == 0) sinv[w] = inv;

  char* prow = pbuf + w * 4096;
  int sw = w << 4;
  #pragma unroll
  for (int it = 0; it < 8; ++it)
    *(uint2*)(prow + (((lane + 64 * it) * 8) ^ sw)) = pva[it];
  __syncthreads();

  // ---- attention stores issue now; drain overlaps the MFMA phase ----
  {
    float* orow = attn_out + ((size_t)(b * NN + i)) * NN;
    #pragma unroll
    for (int it = 0; it < 8; ++it) {
      uint2 w2 = pva[it];
      f32x4 v;
      v.x = bf2f((ushort)(w2.x & 0xffff)) * inv;
      v.y = bf2f((ushort)(w2.x >> 16)) * inv;
      v.z = bf2f((ushort)(w2.y & 0xffff)) * inv;
      v.w = bf2f((ushort)(w2.y >> 16)) * inv;
      __builtin_nontemporal_store(v, (f32x4*)(orow + (lane + 64 * it) * 4));
    }
  }

  // ---- Phase 2: MFMA p @ Wh; wave = (ntile = w>>1, khalf = w&1) ----
  int ntile = w >> 1, khalf = w & 1;
  int o0 = ntile * 16;
  int lo16 = lane & 15, hi4 = lane >> 4;

  const char* prowA = pbuf + (lo16 & 7) * 4096;
  int swA = (lo16 & 7) << 4;
  const ushort* brow = WhbfT + ((size_t)(b * OUT_F + o0 + lo16)) * NN;
  short8 zero8 = {0, 0, 0, 0, 0, 0, 0, 0};

  f32x4 acc = {0.f, 0.f, 0.f, 0.f};
  #pragma unroll 4
  for (int kk = 0; kk < 32; ++kk) {
    int kbase = khalf * 1024 + kk * 32 + hi4 * 8;
    short8 afrag = *(const short8*)(prowA + ((kbase * 2) ^ swA));
    afrag = lo16 < 8 ? afrag : zero8;        // rows 8..15 of A are zero
    short8 bfrag = *(const short8*)(brow + kbase);
    acc = __builtin_amdgcn_mfma_f32_16x16x32_bf16(afrag, bfrag, acc, 0, 0, 0);
  }

  // ---- cross-khalf reduce + epilogue (valid C rows: 0..7) ----
  if (khalf == 1) {
    #pragma unroll
    for (int q = 0; q < 4; ++q) red[ntile][hi4 * 4 + q][lo16] = acc[q];
  }
  __syncthreads();
  if (khalf == 0 && hi4 < 2) {
    #pragma unroll
    for (int q = 0; q < 4; ++q) {
      int crow = hi4 * 4 + q;
      float v = (acc[q] + red[ntile][crow][lo16]) * sinv[crow];
      v = v > 0.f ? v : 0.01f * v;           // leaky_relu 0.01
      hprime[((size_t)(b * NN + i0 + crow)) * OUT_F + o0 + lo16] = v;
    }
  }
}

extern "C" void kernel_launch(void* const* d_in, const int* in_sizes, int n_in,
                              void* d_out, int out_size, void* d_ws, size_t ws_size,
                              hipStream_t stream) {
  const float* h  = (const float*)d_in[0];
  const int* adj  = (const int*)d_in[1];
  const float* W  = (const float*)d_in[2];
  const float* a  = (const float*)d_in[3];

  float* hprime   = (float*)d_out;                           // B*N*OUT_F
  float* attn_out = (float*)d_out + (size_t)BB * NN * OUT_F; // B*N*N

  // workspace: Whbf bf16 [B*N*64], WhbfT bf16 [B*64*N], el f32, er f32
  ushort* Whbf  = (ushort*)d_ws;
  ushort* WhbfT = Whbf + (size_t)BB * NN * OUT_F;
  float* el = (float*)(WhbfT + (size_t)BB * OUT_F * NN);
  float* er = el + (size_t)BB * NN;

  hipLaunchKernelGGL(wh_el_er_kernel, dim3(BB * NN), dim3(64), 0, stream,
                     h, W, a, Whbf, el, er);
  hipLaunchKernelGGL(transpose_kernel, dim3(BB * (NN / 64)), dim3(256), 0, stream,
                     Whbf, WhbfT);
  hipLaunchKernelGGL(attn_kernel, dim3(BB * (NN / 8)), dim3(512), 0, stream,
                     adj, WhbfT, el, er, attn_out, hprime);
}

// Round 8
// 52.224 us; speedup vs baseline: 1.8626x; 1.1773x over previous
//
#include <hip/hip_runtime.h>

#define NN 2048
#define BB 4
#define IN_F 128
#define OUT_F 64

typedef __attribute__((ext_vector_type(8))) short short8;
typedef __attribute__((ext_vector_type(4))) float f32x4;
typedef __attribute__((ext_vector_type(4))) int i32x4;

__device__ __forceinline__ ushort f2bf(float f) {
  uint u = __float_as_uint(f);
  uint r = (u + 0x7fffu + ((u >> 16) & 1u)) >> 16;   // RNE, finite values
  return (ushort)r;
}
__device__ __forceinline__ float bf2f(ushort s) {
  return __uint_as_float(((uint)s) << 16);
}

// Kernel 1: per row: wh[o] = h[row].W[:,o] (f32) -> Whbf bf16 row-major;
// el/er via wave reduce.
__global__ __launch_bounds__(64) void wh_el_er_kernel(
    const float* __restrict__ h, const float* __restrict__ W,
    const float* __restrict__ a, ushort* __restrict__ Whbf,
    float* __restrict__ el, float* __restrict__ er) {
  int row = blockIdx.x;           // b*NN + n
  int o = threadIdx.x;
  const float* hr = h + (size_t)row * IN_F;
  float wh = 0.f;
  #pragma unroll 8
  for (int f = 0; f < IN_F; ++f) wh += hr[f] * W[f * OUT_F + o];
  Whbf[(size_t)row * OUT_F + o] = f2bf(wh);
  float vl = wh * a[o];
  float vr = wh * a[OUT_F + o];
  #pragma unroll
  for (int d = 32; d > 0; d >>= 1) {
    vl += __shfl_down(vl, d);
    vr += __shfl_down(vr, d);
  }
  if (o == 0) { el[row] = vl; er[row] = vr; }
}

// Kernel 1b: WhbfT[b][o][j] = Whbf[b][j][o] (bf16 transpose, 64x2048/batch).
__global__ __launch_bounds__(256) void transpose_kernel(
    const ushort* __restrict__ Whbf, ushort* __restrict__ WhbfT) {
  __shared__ uint tile[64][65];
  int b = blockIdx.x >> 5;
  int j0 = (blockIdx.x & 31) << 6;
  int t = threadIdx.x;
  int o = t & 63, jg = t >> 6;
  #pragma unroll
  for (int m = 0; m < 16; ++m) {
    int jj = jg * 16 + m;
    tile[jj][o] = (uint)Whbf[((size_t)(b * NN + j0 + jj)) * OUT_F + o];
  }
  __syncthreads();
  int oo = t >> 2, grp = t & 3;
  uint out[8];
  #pragma unroll
  for (int m = 0; m < 16; m += 2) {
    uint u0 = tile[grp * 16 + m][oo];
    uint u1 = tile[grp * 16 + m + 1][oo];
    out[m >> 1] = u0 | (u1 << 16);
  }
  uint4* dst = (uint4*)(WhbfT + ((size_t)(b * OUT_F + oo)) * NN + j0 + grp * 16);
  dst[0] = *(uint4*)&out[0];
  dst[1] = *(uint4*)&out[4];
}

// Kernel 2: block = 16 rows of one batch, 512 threads (8 waves), 2 rows/wave.
// er staged once in LDS. Phase 1: both rows' adj loads INTERLEAVED in one
// loop (2x loads in flight), streaming no-max masked exp, unnormalized bf16
// p -> regs + XOR-swizzled 64 KB pbuf. Barrier -> PLAIN coalesced attention
// stores (drain overlaps MFMA below) -> Phase 2: MFMA p @ Wh
// (wave = ntile x khalf), cross-khalf LDS reduce, scale 1/s, lrelu 0.01.
__global__ __launch_bounds__(512, 4) void attn_kernel(
    const int* __restrict__ adj, const ushort* __restrict__ WhbfT,
    const float* __restrict__ el, const float* __restrict__ er,
    float* __restrict__ attn_out, float* __restrict__ hprime) {
  __shared__ __align__(16) char pbuf[16 * 4096];  // 64 KB: p bf16 [16][2048]
  __shared__ float ers[NN];                       // 8 KB
  __shared__ float red[4][16][17];                // 4.4 KB cross-khalf reduce
  __shared__ float sinv[16];

  int blk = blockIdx.x;
  int b = blk >> 7;             // 128 blocks per batch
  int i0 = (blk & 127) << 4;
  int tid = threadIdx.x;
  int wave = tid >> 6, lane = tid & 63;

  // stage er for this batch into LDS
  ((f32x4*)ers)[tid] = ((const f32x4*)(er + (size_t)b * NN))[tid];
  __syncthreads();

  // ---- Phase 1: both rows interleaved, coalesced, no-max streaming exp ----
  int r0 = wave * 2, r1 = r0 + 1;
  int ia = i0 + r0, ib = i0 + r1;
  float el0 = el[(size_t)b * NN + ia];
  float el1 = el[(size_t)b * NN + ib];
  const i32x4* arow0 = (const i32x4*)(adj + ((size_t)(b * NN + ia)) * NN);
  const i32x4* arow1 = (const i32x4*)(adj + ((size_t)(b * NN + ib)) * NN);

  uint2 pva0[8], pva1[8];
  float ss0 = 0.f, ss1 = 0.f;
  #pragma unroll
  for (int it = 0; it < 8; ++it) {
    i32x4 a0 = arow0[lane + 64 * it];
    i32x4 a1 = arow1[lane + 64 * it];
    f32x4 ev = *(const f32x4*)&ers[(lane + 64 * it) * 4];
    float evv[4] = {ev.x, ev.y, ev.z, ev.w};
    int   av0[4] = {a0.x, a0.y, a0.z, a0.w};
    int   av1[4] = {a1.x, a1.y, a1.z, a1.w};
    float pe0[4], pe1[4];
    #pragma unroll
    for (int k = 0; k < 4; ++k) {
      float e0 = el0 + evv[k];
      e0 = e0 > 0.f ? e0 : 0.2f * e0;       // leaky_relu 0.2
      float x0 = __expf(e0);                // |e| <~ 12, f32-safe unnormalized
      pe0[k] = av0[k] > 0 ? x0 : 0.f;
      ss0 += pe0[k];
      float e1 = el1 + evv[k];
      e1 = e1 > 0.f ? e1 : 0.2f * e1;
      float x1 = __expf(e1);
      pe1[k] = av1[k] > 0 ? x1 : 0.f;
      ss1 += pe1[k];
    }
    uint2 w0, w1;
    w0.x = (uint)f2bf(pe0[0]) | ((uint)f2bf(pe0[1]) << 16);
    w0.y = (uint)f2bf(pe0[2]) | ((uint)f2bf(pe0[3]) << 16);
    w1.x = (uint)f2bf(pe1[0]) | ((uint)f2bf(pe1[1]) << 16);
    w1.y = (uint)f2bf(pe1[2]) | ((uint)f2bf(pe1[3]) << 16);
    pva0[it] = w0;
    pva1[it] = w1;
  }
  #pragma unroll
  for (int d = 32; d > 0; d >>= 1) {
    ss0 += __shfl_xor(ss0, d);
    ss1 += __shfl_xor(ss1, d);
  }
  float inv0 = 1.f / ss0, inv1 = 1.f / ss1;
  if (lane == 0) { sinv[r0] = inv0; sinv[r1] = inv1; }

  {
    char* prow0 = pbuf + r0 * 4096;
    char* prow1 = pbuf + r1 * 4096;
    int sw0 = (r0 & 7) << 4, sw1 = (r1 & 7) << 4;
    #pragma unroll
    for (int it = 0; it < 8; ++it) {
      *(uint2*)(prow0 + (((lane + 64 * it) * 8) ^ sw0)) = pva0[it];
      *(uint2*)(prow1 + (((lane + 64 * it) * 8) ^ sw1)) = pva1[it];
    }
  }
  __syncthreads();

  // ---- attention stores (plain, coalesced); drain overlaps MFMA phase ----
  {
    f32x4* or0 = (f32x4*)(attn_out + ((size_t)(b * NN + ia)) * NN);
    f32x4* or1 = (f32x4*)(attn_out + ((size_t)(b * NN + ib)) * NN);
    #pragma unroll
    for (int it = 0; it < 8; ++it) {
      uint2 w0 = pva0[it], w1 = pva1[it];
      f32x4 v0, v1;
      v0.x = bf2f((ushort)(w0.x & 0xffff)) * inv0;
      v0.y = bf2f((ushort)(w0.x >> 16)) * inv0;
      v0.z = bf2f((ushort)(w0.y & 0xffff)) * inv0;
      v0.w = bf2f((ushort)(w0.y >> 16)) * inv0;
      or0[lane + 64 * it] = v0;
      v1.x = bf2f((ushort)(w1.x & 0xffff)) * inv1;
      v1.y = bf2f((ushort)(w1.x >> 16)) * inv1;
      v1.z = bf2f((ushort)(w1.y & 0xffff)) * inv1;
      v1.w = bf2f((ushort)(w1.y >> 16)) * inv1;
      or1[lane + 64 * it] = v1;
    }
  }

  // ---- Phase 2: MFMA p @ Wh; wave = (ntile = w>>1, khalf = w&1) ----
  int ntile = wave >> 1, khalf = wave & 1;
  int o0 = ntile * 16;
  int lo16 = lane & 15, hi4 = lane >> 4;

  const char* prowA = pbuf + lo16 * 4096;
  int swA = (lo16 & 7) << 4;
  const ushort* brow = WhbfT + ((size_t)(b * OUT_F + o0 + lo16)) * NN;

  f32x4 acc = {0.f, 0.f, 0.f, 0.f};
  #pragma unroll 4
  for (int kk = 0; kk < 32; ++kk) {
    int kbase = khalf * 1024 + kk * 32 + hi4 * 8;
    short8 afrag = *(const short8*)(prowA + ((kbase * 2) ^ swA));
    short8 bfrag = *(const short8*)(brow + kbase);
    acc = __builtin_amdgcn_mfma_f32_16x16x32_bf16(afrag, bfrag, acc, 0, 0, 0);
  }

  // ---- cross-khalf reduce + epilogue ----
  if (khalf == 1) {
    #pragma unroll
    for (int q = 0; q < 4; ++q) red[ntile][hi4 * 4 + q][lo16] = acc[q];
  }
  __syncthreads();
  if (khalf == 0) {
    #pragma unroll
    for (int q = 0; q < 4; ++q) {
      int crow = hi4 * 4 + q;
      float v = (acc[q] + red[ntile][crow][lo16]) * sinv[crow];
      v = v > 0.f ? v : 0.01f * v;           // leaky_relu 0.01
      hprime[((size_t)(b * NN + i0 + crow)) * OUT_F + o0 + lo16] = v;
    }
  }
}

extern "C" void kernel_launch(void* const* d_in, const int* in_sizes, int n_in,
                              void* d_out, int out_size, void* d_ws, size_t ws_size,
                              hipStream_t stream) {
  const float* h  = (const float*)d_in[0];
  const int* adj  = (const int*)d_in[1];
  const float* W  = (const float*)d_in[2];
  const float* a  = (const float*)d_in[3];

  float* hprime   = (float*)d_out;                           // B*N*OUT_F
  float* attn_out = (float*)d_out + (size_t)BB * NN * OUT_F; // B*N*N

  // workspace: Whbf bf16 [B*N*64], WhbfT bf16 [B*64*N], el f32, er f32
  ushort* Whbf  = (ushort*)d_ws;
  ushort* WhbfT = Whbf + (size_t)BB * NN * OUT_F;
  float* el = (float*)(WhbfT + (size_t)BB * OUT_F * NN);
  float* er = el + (size_t)BB * NN;

  hipLaunchKernelGGL(wh_el_er_kernel, dim3(BB * NN), dim3(64), 0, stream,
                     h, W, a, Whbf, el, er);
  hipLaunchKernelGGL(transpose_kernel, dim3(BB * (NN / 64)), dim3(256), 0, stream,
                     Whbf, WhbfT);
  hipLaunchKernelGGL(attn_kernel, dim3(BB * (NN / 16)), dim3(512), 0, stream,
                     adj, WhbfT, el, er, attn_out, hprime);
}